// Round 9
// baseline (164.932 us; speedup 1.0000x reference)
//
#include <hip/hip_runtime.h>

typedef unsigned short u16;
typedef unsigned int   u32;
typedef __attribute__((ext_vector_type(8))) short bf16x8;   // 8 bf16 = 4 VGPRs
typedef __attribute__((ext_vector_type(4))) short bf16x4;   // 4 bf16 = 2 VGPRs
typedef __attribute__((ext_vector_type(4))) float f32x4;    // MFMA 16x16 accumulator

union F8 { bf16x8 v; u32 u[4]; };
union F4 { bf16x4 v; u32 u[2]; };

__device__ __forceinline__ u16 f2b(float f) {
    unsigned u = __builtin_bit_cast(unsigned, f);
    return (u16)((u + 0x7FFFu + ((u >> 16) & 1u)) >> 16);   // RNE fp32->bf16
}
__device__ __forceinline__ u32 pkbf(float a, float b) {     // RNE pack (proven)
    return ((u32)f2b(b) << 16) | (u32)f2b(a);
}

// K=16 MFMA from packed-pair (bf16x4) operands, built ONLY from the proven
// K=32 instruction: data in k-slots 0-3, zeros in 4-7, on BOTH operands ->
// slot i pairs with slot i (k32 = 8g+i on both sides). Exact.
// (The _1k legacy builtin NaN'd on gfx950 — never use unverified MFMAs.)
__device__ __forceinline__ f32x4 mfma16(F4 a, F4 b, f32x4 c) {
    F8 a8, b8;
    a8.u[0] = a.u[0]; a8.u[1] = a.u[1]; a8.u[2] = 0; a8.u[3] = 0;
    b8.u[0] = b.u[0]; b8.u[1] = b.u[1]; b8.u[2] = 0; b8.u[3] = 0;
    return __builtin_amdgcn_mfma_f32_16x16x32_bf16(a8.v, b8.v, c, 0, 0, 0);
}

// ---------------------------------------------------------------------------
// Prep: bf16 MFMA weight fragments. Fragment f at ushort f*512,
// elem(l,i) = W[k = ks*32 + (l>>4)*8 + i][col = nt*16 + (l&15)].
// Bias table expanded to [h][query][key] fp32 at float offset 32768.
// ---------------------------------------------------------------------------
__global__ void prep_kernel(const float* __restrict__ qkv_w,
                            const float* __restrict__ proj_w,
                            const float* __restrict__ bias_tbl,
                            u16* __restrict__ wsb, float* __restrict__ wsf)
{
    int tid = blockIdx.x * 256 + threadIdx.x;
    if (tid < 49152) {                      // qkv_w fragments
        int i = tid & 7, l = (tid >> 3) & 63, f = tid >> 9;
        int nt = f >> 2, ks = f & 3;
        int k = ks * 32 + (l >> 4) * 8 + i;
        int col = nt * 16 + (l & 15);
        wsb[tid] = f2b(qkv_w[k * 384 + col]);
    } else if (tid < 65536) {               // proj_w fragments
        int e = tid - 49152;
        int i = e & 7, l = (e >> 3) & 63, f = e >> 9;
        int nt = f >> 2, ks = f & 3;
        int k = ks * 32 + (l >> 4) * 8 + i;
        int col = nt * 16 + (l & 15);
        wsb[tid] = f2b(proj_w[k * 128 + col]);
    } else if (tid < 66560) {               // bias expand: [h][t1=query][t2=key]
        int e = tid - 65536;
        int h = e >> 8, t1 = (e >> 4) & 15, t2 = e & 15;
        int idx = ((t1 >> 2) - (t2 >> 2) + 3) * 7 + ((t1 & 3) - (t2 & 3) + 3);
        wsf[32768 + e] = bias_tbl[idx * 4 + h];
    }
}

// ---------------------------------------------------------------------------
// Fused window attention: ONE window per wave, 4 waves/block, ZERO LDS, zero
// barriers. qkv D-frags [col 4g+r][tok q16] are used directly as K=16 MFMA
// operands; softmax output is directly the PV B-frag; the PV A-frag (V^T) is
// built by an in-register shfl transpose of the V D-frags.
// ---------------------------------------------------------------------------
__global__ __launch_bounds__(256, 4) void winattn_kernel(
    const float* __restrict__ x, const u16* __restrict__ wfrag,
    const float* __restrict__ qkv_b, const float* __restrict__ proj_b,
    const float* __restrict__ biasx, float* __restrict__ out)
{
    const int tid  = threadIdx.x;
    const int lane = tid & 63;
    const int g = lane >> 4, q16 = lane & 15;
    const int wid = blockIdx.x * 4 + (tid >> 6);
    const int b = wid >> 10, rem = wid & 1023, wi = rem >> 5, wj = rem & 31;

    // lane's token row (token = q16)
    const int nTok = (wi * 4 + (q16 >> 2)) * 128 + wj * 4 + (q16 & 3);
    const float* xrow = x + ((long)b * 16384 + nTok) * 128;

    // x^T B-fragments: lane holds x[tok q16][ch = ks*32 + g*8 + i]
    F8 ax[4];
    #pragma unroll
    for (int ks = 0; ks < 4; ++ks) {
        const float4* p = (const float4*)(xrow + ks * 32 + g * 8);
        float4 v0 = p[0], v1 = p[1];
        ax[ks].u[0] = pkbf(v0.x, v0.y); ax[ks].u[1] = pkbf(v0.z, v0.w);
        ax[ks].u[2] = pkbf(v1.x, v1.y); ax[ks].u[3] = pkbf(v1.z, v1.w);
    }

    const bf16x8* wv = (const bf16x8*)wfrag;

    // ---- qkv^T GEMM: D[col nt*16+4g+r][tok q16] held packed in registers ---
    u32 Qpk[8][2], Kpk[8][2], Vpk[8][2];
    #pragma unroll
    for (int nt = 0; nt < 8; ++nt) {        // Q tiles
        float4 bb = *(const float4*)&qkv_b[nt * 16 + 4 * g];
        f32x4 acc = {bb.x, bb.y, bb.z, bb.w};
        #pragma unroll
        for (int ks = 0; ks < 4; ++ks)
            acc = __builtin_amdgcn_mfma_f32_16x16x32_bf16(wv[(nt * 4 + ks) * 64 + lane],
                                                          ax[ks].v, acc, 0, 0, 0);
        Qpk[nt][0] = pkbf(acc[0], acc[1]); Qpk[nt][1] = pkbf(acc[2], acc[3]);
    }
    #pragma unroll
    for (int nt = 8; nt < 16; ++nt) {       // K tiles
        float4 bb = *(const float4*)&qkv_b[nt * 16 + 4 * g];
        f32x4 acc = {bb.x, bb.y, bb.z, bb.w};
        #pragma unroll
        for (int ks = 0; ks < 4; ++ks)
            acc = __builtin_amdgcn_mfma_f32_16x16x32_bf16(wv[(nt * 4 + ks) * 64 + lane],
                                                          ax[ks].v, acc, 0, 0, 0);
        Kpk[nt - 8][0] = pkbf(acc[0], acc[1]); Kpk[nt - 8][1] = pkbf(acc[2], acc[3]);
    }
    #pragma unroll
    for (int nt = 16; nt < 24; ++nt) {      // V tiles (stay in registers)
        float4 bb = *(const float4*)&qkv_b[nt * 16 + 4 * g];
        f32x4 acc = {bb.x, bb.y, bb.z, bb.w};
        #pragma unroll
        for (int ks = 0; ks < 4; ++ks)
            acc = __builtin_amdgcn_mfma_f32_16x16x32_bf16(wv[(nt * 4 + ks) * 64 + lane],
                                                          ax[ks].v, acc, 0, 0, 0);
        Vpk[nt - 16][0] = pkbf(acc[0], acc[1]); Vpk[nt - 16][1] = pkbf(acc[2], acc[3]);
    }

    // ---- attention: K=16 MFMAs; V^T A-frag via in-register shfl transpose --
    // Target (chunk c): lane (g,q16) needs V^T[d=c*16+q16][key=4g+i], i=0..3.
    // Source: Vpk[c][j] at lane (g',t') = (V^T[c*16+4g'+2j][t'], [..+1][t']).
    // => src lane = (q16>>2)*16 + 4g + i; j = (q16&3)>>1; half = q16&1.
    // Shuffle BOTH j-entries, select by the TARGET lane's j after the shfl
    // (the source lane's own j differs!).
    const float scale = 0.17677669529663689f;   // 32^-0.5
    const int vS  = ((q16 >> 2) << 4) + 4 * g;  // shfl source base lane
    const int vsh = (q16 & 1) * 16;             // half-select shift
    const bool jhi = (q16 & 2) != 0;            // pair index within Vpk[c]
    f32x4 z4 = {0.f, 0.f, 0.f, 0.f};
    u32 Opk[8][2];                              // O^T D-frags per 16-d chunk

    #pragma unroll
    for (int h = 0; h < 4; ++h) {
        // S^T = K Q^T : D-frags of K/Q used directly as A/B (chunks 2h, 2h+1)
        F4 k0, k1, q0, q1;
        k0.u[0] = Kpk[2*h][0];   k0.u[1] = Kpk[2*h][1];
        k1.u[0] = Kpk[2*h+1][0]; k1.u[1] = Kpk[2*h+1][1];
        q0.u[0] = Qpk[2*h][0];   q0.u[1] = Qpk[2*h][1];
        q1.u[0] = Qpk[2*h+1][0]; q1.u[1] = Qpk[2*h+1][1];
        f32x4 s = mfma16(k0, q0, z4); s = mfma16(k1, q1, s);

        // lane holds S^T[key 4g+r][q q16]; softmax over keys (r + xor16/32)
        float4 bias4 = *(const float4*)&biasx[(h * 16 + q16) * 16 + 4 * g];
        float a0 = s[0] * scale + bias4.x, a1 = s[1] * scale + bias4.y;
        float a2 = s[2] * scale + bias4.z, a3 = s[3] * scale + bias4.w;
        float m = fmaxf(fmaxf(a0, a1), fmaxf(a2, a3));
        m = fmaxf(m, __shfl_xor(m, 16, 64));
        m = fmaxf(m, __shfl_xor(m, 32, 64));
        float e0 = __expf(a0 - m), e1 = __expf(a1 - m);
        float e2 = __expf(a2 - m), e3 = __expf(a3 - m);
        float su = e0 + e1 + e2 + e3;
        su += __shfl_xor(su, 16, 64);
        su += __shfl_xor(su, 32, 64);
        float rs = 1.0f / su;
        F4 pP; pP.u[0] = pkbf(e0 * rs, e1 * rs); pP.u[1] = pkbf(e2 * rs, e3 * rs);

        // O^T = V^T P^T per 16-d chunk
        #pragma unroll
        for (int dt = 0; dt < 2; ++dt) {
            int c = 2 * h + dt;
            u32 y00 = (u32)__shfl((int)Vpk[c][0], vS + 0, 64);
            u32 y10 = (u32)__shfl((int)Vpk[c][1], vS + 0, 64);
            u32 y01 = (u32)__shfl((int)Vpk[c][0], vS + 1, 64);
            u32 y11 = (u32)__shfl((int)Vpk[c][1], vS + 1, 64);
            u32 y02 = (u32)__shfl((int)Vpk[c][0], vS + 2, 64);
            u32 y12 = (u32)__shfl((int)Vpk[c][1], vS + 2, 64);
            u32 y03 = (u32)__shfl((int)Vpk[c][0], vS + 3, 64);
            u32 y13 = (u32)__shfl((int)Vpk[c][1], vS + 3, 64);
            u32 x0 = jhi ? y10 : y00, x1 = jhi ? y11 : y01;
            u32 x2 = jhi ? y12 : y02, x3 = jhi ? y13 : y03;
            F4 vf;
            vf.u[0] = ((x0 >> vsh) & 0xffffu) | (((x1 >> vsh) & 0xffffu) << 16);
            vf.u[1] = ((x2 >> vsh) & 0xffffu) | (((x3 >> vsh) & 0xffffu) << 16);
            f32x4 o = mfma16(vf, pP, z4);
            Opk[c][0] = pkbf(o[0], o[1]); Opk[c][1] = pkbf(o[2], o[3]);
        }
    }

    // proj B-frags af: [ch ks*32+g*8+i][tok q16] via packed-pair shfl
    const int s0  = (2 * (g & 1)) * 16 + q16;
    const int s1  = s0 + 16;
    const int sel = g >> 1;
    F8 af[4];
    #pragma unroll
    for (int ks = 0; ks < 4; ++ks)
        #pragma unroll
        for (int j = 0; j < 4; ++j) {
            int src = (j < 2) ? s0 : s1;
            u32 lo = (u32)__shfl((int)Opk[2*ks][j & 1], src, 64);
            u32 hi = (u32)__shfl((int)Opk[2*ks+1][j & 1], src, 64);
            af[ks].u[j] = sel ? hi : lo;
        }

    // ---- proj^T GEMM + store ----
    const long obase = ((long)b * 16384 + nTok) * 128;
    #pragma unroll 2
    for (int nt = 0; nt < 8; ++nt) {
        float4 bb = *(const float4*)&proj_b[nt * 16 + 4 * g];
        f32x4 acc = {bb.x, bb.y, bb.z, bb.w};
        #pragma unroll
        for (int ks = 0; ks < 4; ++ks)
            acc = __builtin_amdgcn_mfma_f32_16x16x32_bf16(wv[(96 + nt * 4 + ks) * 64 + lane],
                                                          af[ks].v, acc, 0, 0, 0);
        float4 o; o.x = acc[0]; o.y = acc[1]; o.z = acc[2]; o.w = acc[3];
        *(float4*)&out[obase + nt * 16 + 4 * g] = o;
    }
}

extern "C" void kernel_launch(void* const* d_in, const int* in_sizes, int n_in,
                              void* d_out, int out_size, void* d_ws, size_t ws_size,
                              hipStream_t stream)
{
    const float* x        = (const float*)d_in[0];
    const float* qkv_w    = (const float*)d_in[3];
    const float* qkv_b    = (const float*)d_in[4];
    const float* proj_w   = (const float*)d_in[5];
    const float* proj_b   = (const float*)d_in[6];
    const float* bias_tbl = (const float*)d_in[7];

    u16*   wsb = (u16*)d_ws;
    float* wsf = (float*)d_ws;

    prep_kernel<<<260, 256, 0, stream>>>(qkv_w, proj_w, bias_tbl, wsb, wsf);
    winattn_kernel<<<4096, 256, 0, stream>>>(x, wsb, qkv_b, proj_b,
                                             wsf + 32768, (float*)d_out);
}

// Round 11
// 141.762 us; speedup vs baseline: 1.1634x; 1.1634x over previous
//
#include <hip/hip_runtime.h>

typedef unsigned short u16;
typedef unsigned int   u32;
typedef __attribute__((ext_vector_type(8))) short bf16x8;   // 8 bf16 = 4 VGPRs
typedef __attribute__((ext_vector_type(4))) short bf16x4;   // 4 bf16 = 2 VGPRs
typedef __attribute__((ext_vector_type(4))) float f32x4;    // MFMA 16x16 accumulator
typedef __attribute__((ext_vector_type(2))) u32 u32x2;

union F8 { bf16x8 v; u32 u[4]; };
union F4 { bf16x4 v; u32 u[2]; };

__device__ __forceinline__ u16 f2b(float f) {
    unsigned u = __builtin_bit_cast(unsigned, f);
    return (u16)((u + 0x7FFFu + ((u >> 16) & 1u)) >> 16);   // RNE fp32->bf16
}
// Bit-op RNE pack. (gfx950 lessons: asm v_cvt_pk_bf16_f32 gave 2.25e-2 error
// in R10 — wrong semantics for this use; _1k MFMA builtins NaN. Use neither.)
__device__ __forceinline__ u32 pkbf(float a, float b) {
    return ((u32)f2b(b) << 16) | (u32)f2b(a);
}

// K=16 MFMA from packed-pair (bf16x4) operands, via the PROVEN K=32 instruction:
// data in k-slots 0-3, zeros in 4-7, identically on both operands -> exact.
__device__ __forceinline__ f32x4 mfma16(F4 a, F4 b, f32x4 c) {
    F8 a8, b8;
    a8.u[0] = a.u[0]; a8.u[1] = a.u[1]; a8.u[2] = 0; a8.u[3] = 0;
    b8.u[0] = b.u[0]; b8.u[1] = b.u[1]; b8.u[2] = 0; b8.u[3] = 0;
    return __builtin_amdgcn_mfma_f32_16x16x32_bf16(a8.v, b8.v, c, 0, 0, 0);
}

// ---------------------------------------------------------------------------
// Prep.
//  ushort [0, 49152): qkv K=32 B-frags, frag f=(nt*4+ks) at f*512:
//    elem(l,i) = qkv_w[k=ks*32+(l>>4)*8+i][col=nt*16+(l&15)], Q cols pre-scaled.
//  u32 [24576, 32768): proj K=16 A-frags, frag (nt*8+c) stride 128 u32:
//    u[j](l) = pack(Wp[d=c*16+4*(l>>4)+2j][col=nt*16+(l&15)], Wp[d+1][col]).
//  float 32768..33791: bias dense [h][query][key].
//  float 33792..34175: qkv_b with Q part pre-scaled.
// ---------------------------------------------------------------------------
__global__ void prep_kernel(const float* __restrict__ qkv_w,
                            const float* __restrict__ proj_w,
                            const float* __restrict__ bias_tbl,
                            const float* __restrict__ qkv_b,
                            u16* __restrict__ wsb, float* __restrict__ wsf)
{
    const float scale = 0.17677669529663689f;   // 32^-0.5
    int tid = blockIdx.x * 256 + threadIdx.x;
    if (tid < 49152) {                      // qkv_w fragments (Q pre-scaled)
        int i = tid & 7, l = (tid >> 3) & 63, f = tid >> 9;
        int nt = f >> 2, ks = f & 3;
        int k = ks * 32 + (l >> 4) * 8 + i;
        int col = nt * 16 + (l & 15);
        float w = qkv_w[k * 384 + col];
        if (col < 128) w *= scale;
        wsb[tid] = f2b(w);
    } else if (tid < 57344) {               // proj K=16 fragments
        int e = tid - 49152;                // one u32 each
        int j = e & 1, l = (e >> 1) & 63, f = e >> 7;
        int c = f & 7, nt = f >> 3;
        int col = nt * 16 + (l & 15);
        int d = c * 16 + 4 * (l >> 4) + 2 * j;
        u32 val = ((u32)f2b(proj_w[(d + 1) * 128 + col]) << 16)
                |  (u32)f2b(proj_w[d * 128 + col]);
        ((u32*)wsb)[24576 + f * 128 + l * 2 + j] = val;
    } else if (tid < 58368) {               // bias expand: [h][query][key]
        int e = tid - 57344;
        int h = e >> 8, t1 = (e >> 4) & 15, t2 = e & 15;
        int idx = ((t1 >> 2) - (t2 >> 2) + 3) * 7 + ((t1 & 3) - (t2 & 3) + 3);
        wsf[32768 + e] = bias_tbl[idx * 4 + h];
    } else if (tid < 58752) {               // qkv_b, Q part pre-scaled
        int e = tid - 58368;
        wsf[33792 + e] = qkv_b[e] * (e < 128 ? scale : 1.0f);
    }
}

// ---------------------------------------------------------------------------
// Fused window attention: 4 waves/block, TWO windows/wave (A=even, B=odd wj).
// ZERO cross-lane shfl/swizzle anywhere:
//  - qkv D-frags [col 4g+r][tok q16] used directly as K=16 MFMA operands.
//  - softmax: no max-sub (scale folded, args tiny); denominator via
//    ones-A-frag MFMA (key-reduction in the MFMA k-dim) -> su in-lane.
//  - PV output scaled by 1/su, packed -> directly the proj B-operand.
// V through per-wave-PRIVATE LDS; in-wave lgkmcnt(0) ordering, no barrier.
// ---------------------------------------------------------------------------
__global__ __launch_bounds__(256, 4) void winattn_kernel(
    const float* __restrict__ x, const u16* __restrict__ wfrag,
    const float* __restrict__ proj_b, float* __restrict__ out)
{
    __shared__ alignas(16) u16 lds[4][4608];     // per-wave vT [128 ch][36]
    const float* wsf    = (const float*)wfrag;
    const float* biasx  = wsf + 32768;
    const float* qkvb2  = wsf + 33792;
    const int tid  = threadIdx.x;
    const int wave = tid >> 6, lane = tid & 63;
    const int g = lane >> 4, q16 = lane & 15;
    u16* vT = lds[wave];

    const int wpair = blockIdx.x * 4 + wave;
    const int wid0  = wpair * 2;                 // window A; B = wid0+1
    const int b = wid0 >> 10, rem = wid0 & 1023, wi = rem >> 5, wj = rem & 31;

    const int nTokA = (wi * 4 + (q16 >> 2)) * 128 + wj * 4 + (q16 & 3);
    const float* xrowA = x + ((long)b * 16384 + nTokA) * 128;
    const float* xrowB = xrowA + 512;

    // x^T B-fragments
    F8 axA[4], axB[4];
    #pragma unroll
    for (int ks = 0; ks < 4; ++ks) {
        const float4* pA = (const float4*)(xrowA + ks * 32 + g * 8);
        float4 a0 = pA[0], a1 = pA[1];
        axA[ks].u[0] = pkbf(a0.x, a0.y); axA[ks].u[1] = pkbf(a0.z, a0.w);
        axA[ks].u[2] = pkbf(a1.x, a1.y); axA[ks].u[3] = pkbf(a1.z, a1.w);
        const float4* pB = (const float4*)(xrowB + ks * 32 + g * 8);
        float4 b0 = pB[0], b1 = pB[1];
        axB[ks].u[0] = pkbf(b0.x, b0.y); axB[ks].u[1] = pkbf(b0.z, b0.w);
        axB[ks].u[2] = pkbf(b1.x, b1.y); axB[ks].u[3] = pkbf(b1.z, b1.w);
    }

    const bf16x8* wv = (const bf16x8*)wfrag;

    // ---- qkv^T GEMM: D[col nt*16+4g+r][tok q16]; one frag -> 2 MFMAs ----
    u32 QpkA[8][2], QpkB[8][2], KpkA[8][2], KpkB[8][2];
    #pragma unroll
    for (int nt = 0; nt < 8; ++nt) {        // Q tiles (pre-scaled)
        float4 bb = *(const float4*)&qkvb2[nt * 16 + 4 * g];
        f32x4 accA = {bb.x, bb.y, bb.z, bb.w}, accB = accA;
        #pragma unroll
        for (int ks = 0; ks < 4; ++ks) {
            bf16x8 frag = wv[(nt * 4 + ks) * 64 + lane];
            accA = __builtin_amdgcn_mfma_f32_16x16x32_bf16(frag, axA[ks].v, accA, 0, 0, 0);
            accB = __builtin_amdgcn_mfma_f32_16x16x32_bf16(frag, axB[ks].v, accB, 0, 0, 0);
        }
        QpkA[nt][0] = pkbf(accA[0], accA[1]); QpkA[nt][1] = pkbf(accA[2], accA[3]);
        QpkB[nt][0] = pkbf(accB[0], accB[1]); QpkB[nt][1] = pkbf(accB[2], accB[3]);
    }
    #pragma unroll
    for (int nt = 8; nt < 16; ++nt) {       // K tiles
        float4 bb = *(const float4*)&qkvb2[nt * 16 + 4 * g];
        f32x4 accA = {bb.x, bb.y, bb.z, bb.w}, accB = accA;
        #pragma unroll
        for (int ks = 0; ks < 4; ++ks) {
            bf16x8 frag = wv[(nt * 4 + ks) * 64 + lane];
            accA = __builtin_amdgcn_mfma_f32_16x16x32_bf16(frag, axA[ks].v, accA, 0, 0, 0);
            accB = __builtin_amdgcn_mfma_f32_16x16x32_bf16(frag, axB[ks].v, accB, 0, 0, 0);
        }
        KpkA[nt - 8][0] = pkbf(accA[0], accA[1]); KpkA[nt - 8][1] = pkbf(accA[2], accA[3]);
        KpkB[nt - 8][0] = pkbf(accB[0], accB[1]); KpkB[nt - 8][1] = pkbf(accB[2], accB[3]);
    }
    #pragma unroll
    for (int nt = 16; nt < 24; ++nt) {      // V tiles -> vT [ch][A:0-15|B:16-31]
        float4 bb = *(const float4*)&qkvb2[nt * 16 + 4 * g];
        f32x4 accA = {bb.x, bb.y, bb.z, bb.w}, accB = accA;
        #pragma unroll
        for (int ks = 0; ks < 4; ++ks) {
            bf16x8 frag = wv[(nt * 4 + ks) * 64 + lane];
            accA = __builtin_amdgcn_mfma_f32_16x16x32_bf16(frag, axA[ks].v, accA, 0, 0, 0);
            accB = __builtin_amdgcn_mfma_f32_16x16x32_bf16(frag, axB[ks].v, accB, 0, 0, 0);
        }
        int dbase = (nt - 16) * 16 + 4 * g;
        #pragma unroll
        for (int r = 0; r < 4; ++r) {
            vT[(dbase + r) * 36 + q16]      = f2b(accA[r]);
            vT[(dbase + r) * 36 + 16 + q16] = f2b(accB[r]);
        }
    }
    // In-wave ordering of cross-lane LDS writes before reads (wave-private
    // region, no inter-wave sharing -> no block barrier needed).
    asm volatile("s_waitcnt lgkmcnt(0)" ::: "memory");
    __builtin_amdgcn_sched_barrier(0);

    // ---- attention: zero cross-lane ops ----
    f32x4 z4 = {0.f, 0.f, 0.f, 0.f};
    F4 ones; ones.u[0] = 0x3f803f80u; ones.u[1] = 0x3f803f80u;
    u32 OpkA[8][2], OpkB[8][2];             // O^T D-frags (= proj B-operands)

    #pragma unroll
    for (int h = 0; h < 4; ++h) {
        F4 kA0, kA1, qA0, qA1, kB0, kB1, qB0, qB1;
        kA0.u[0] = KpkA[2*h][0];   kA0.u[1] = KpkA[2*h][1];
        kA1.u[0] = KpkA[2*h+1][0]; kA1.u[1] = KpkA[2*h+1][1];
        qA0.u[0] = QpkA[2*h][0];   qA0.u[1] = QpkA[2*h][1];
        qA1.u[0] = QpkA[2*h+1][0]; qA1.u[1] = QpkA[2*h+1][1];
        kB0.u[0] = KpkB[2*h][0];   kB0.u[1] = KpkB[2*h][1];
        kB1.u[0] = KpkB[2*h+1][0]; kB1.u[1] = KpkB[2*h+1][1];
        qB0.u[0] = QpkB[2*h][0];   qB0.u[1] = QpkB[2*h][1];
        qB1.u[0] = QpkB[2*h+1][0]; qB1.u[1] = QpkB[2*h+1][1];
        f32x4 sA = mfma16(kA0, qA0, z4); sA = mfma16(kA1, qA1, sA);
        f32x4 sB = mfma16(kB0, qB0, z4); sB = mfma16(kB1, qB1, sB);

        // P = exp(S + bias)  (no max-sub: |args| < 1, overflow-safe)
        float4 bias4 = *(const float4*)&biasx[(h * 16 + q16) * 16 + 4 * g];
        float eA0 = __expf(sA[0] + bias4.x), eA1 = __expf(sA[1] + bias4.y);
        float eA2 = __expf(sA[2] + bias4.z), eA3 = __expf(sA[3] + bias4.w);
        float eB0 = __expf(sB[0] + bias4.x), eB1 = __expf(sB[1] + bias4.y);
        float eB2 = __expf(sB[2] + bias4.z), eB3 = __expf(sB[3] + bias4.w);
        F4 pA; pA.u[0] = pkbf(eA0, eA1); pA.u[1] = pkbf(eA2, eA3);
        F4 pB; pB.u[0] = pkbf(eB0, eB1); pB.u[1] = pkbf(eB2, eB3);

        // denominator via ones-MFMA: D[m][tok] = su[tok] for every m -> in-lane
        f32x4 suA4 = mfma16(ones, pA, z4);
        f32x4 suB4 = mfma16(ones, pB, z4);
        float rsA = 1.0f / suA4[0];
        float rsB = 1.0f / suB4[0];

        // O'^T = V^T P^T per 16-d chunk; normalize by rs; pack
        #pragma unroll
        for (int dt = 0; dt < 2; ++dt) {
            int c = 2 * h + dt;
            F4 vfA = *(const F4*)&vT[(c * 16 + q16) * 36 + 4 * g];
            F4 vfB = *(const F4*)&vT[(c * 16 + q16) * 36 + 16 + 4 * g];
            f32x4 oA = mfma16(vfA, pA, z4);
            f32x4 oB = mfma16(vfB, pB, z4);
            OpkA[c][0] = pkbf(oA[0] * rsA, oA[1] * rsA);
            OpkA[c][1] = pkbf(oA[2] * rsA, oA[3] * rsA);
            OpkB[c][0] = pkbf(oB[0] * rsB, oB[1] * rsB);
            OpkB[c][1] = pkbf(oB[2] * rsB, oB[3] * rsB);
        }
    }

    // ---- proj: K=16 frags x Opk directly (no transpose, no shfl) ----
    const u32* pw = (const u32*)wfrag + 24576;
    const long obaseA = ((long)b * 16384 + nTokA) * 128;
    const long obaseB = obaseA + 512;
    #pragma unroll 2
    for (int nt = 0; nt < 8; ++nt) {
        float4 bb = *(const float4*)&proj_b[nt * 16 + 4 * g];
        f32x4 accA = {bb.x, bb.y, bb.z, bb.w}, accB = accA;
        #pragma unroll
        for (int c = 0; c < 8; ++c) {
            u32x2 w2 = *(const u32x2*)&pw[(nt * 8 + c) * 128 + lane * 2];
            F4 wf; wf.u[0] = w2.x; wf.u[1] = w2.y;
            F4 bA; bA.u[0] = OpkA[c][0]; bA.u[1] = OpkA[c][1];
            F4 bB; bB.u[0] = OpkB[c][0]; bB.u[1] = OpkB[c][1];
            accA = mfma16(wf, bA, accA);
            accB = mfma16(wf, bB, accB);
        }
        float4 oA; oA.x = accA[0]; oA.y = accA[1]; oA.z = accA[2]; oA.w = accA[3];
        *(float4*)&out[obaseA + nt * 16 + 4 * g] = oA;
        float4 oB; oB.x = accB[0]; oB.y = accB[1]; oB.z = accB[2]; oB.w = accB[3];
        *(float4*)&out[obaseB + nt * 16 + 4 * g] = oB;
    }
}

extern "C" void kernel_launch(void* const* d_in, const int* in_sizes, int n_in,
                              void* d_out, int out_size, void* d_ws, size_t ws_size,
                              hipStream_t stream)
{
    const float* x        = (const float*)d_in[0];
    const float* qkv_w    = (const float*)d_in[3];
    const float* qkv_b    = (const float*)d_in[4];
    const float* proj_w   = (const float*)d_in[5];
    const float* proj_b   = (const float*)d_in[6];
    const float* bias_tbl = (const float*)d_in[7];

    u16*   wsb = (u16*)d_ws;
    float* wsf = (float*)d_ws;

    prep_kernel<<<230, 256, 0, stream>>>(qkv_w, proj_w, bias_tbl, qkv_b, wsb, wsf);
    winattn_kernel<<<2048, 256, 0, stream>>>(x, wsb, proj_b, (float*)d_out);
}

// Round 12
// 94.958 us; speedup vs baseline: 1.7369x; 1.4929x over previous
//
#include <hip/hip_runtime.h>

typedef unsigned short u16;
typedef unsigned int   u32;
typedef __attribute__((ext_vector_type(8))) short bf16x8;   // 8 bf16 = 4 VGPRs
typedef __attribute__((ext_vector_type(4))) short bf16x4;   // 4 bf16 = 2 VGPRs
typedef __attribute__((ext_vector_type(4))) float f32x4;    // MFMA 16x16 accumulator
typedef __attribute__((ext_vector_type(2))) u32 u32x2;

union F8 { bf16x8 v; u32 u[4]; };
union F4 { bf16x4 v; u32 u[2]; };

__device__ __forceinline__ u16 f2b(float f) {
    unsigned u = __builtin_bit_cast(unsigned, f);
    return (u16)((u + 0x7FFFu + ((u >> 16) & 1u)) >> 16);   // RNE fp32->bf16
}
// Bit-op RNE pack. (gfx950 lessons: asm v_cvt_pk_bf16_f32 -> 2.25e-2 error;
// _1k MFMA builtins -> NaN. Use neither.)
__device__ __forceinline__ u32 pkbf(float a, float b) {
    return ((u32)f2b(b) << 16) | (u32)f2b(a);
}

// K=16 MFMA via the proven K=32 instruction: data in k-slots 0-3, zeros in
// 4-7, identically on both operands -> exact.
__device__ __forceinline__ f32x4 mfma16(F4 a, F4 b, f32x4 c) {
    F8 a8, b8;
    a8.u[0] = a.u[0]; a8.u[1] = a.u[1]; a8.u[2] = 0; a8.u[3] = 0;
    b8.u[0] = b.u[0]; b8.u[1] = b.u[1]; b8.u[2] = 0; b8.u[3] = 0;
    return __builtin_amdgcn_mfma_f32_16x16x32_bf16(a8.v, b8.v, c, 0, 0, 0);
}

// Stage one 1KB fragment (this wave's quarter of stream tile t) into the LDS
// ring, zero VGPR cost. Stream tile t at byte t*4096; ring slot = t%3.
__device__ __forceinline__ void stage_tile(const u16* wfrag, u16* ldsbase,
                                           int t, int wave, int lane) {
    const char* gp = (const char*)wfrag + (((t * 4 + wave) << 10) | (lane << 4));
    char* lp = (char*)ldsbase + (((t % 3) << 12) | (wave << 10));
    __builtin_amdgcn_global_load_lds(
        (const __attribute__((address_space(1))) void*)gp,
        (__attribute__((address_space(3))) void*)lp, 16, 0, 0);
}

// Counted-vmcnt pipeline waits: own DMA retired, then raw barrier publishes.
// NEVER __syncthreads in the loop (it drains vmcnt to 0 = kills the pipeline).
#define PIPE_WAIT_1 { asm volatile("s_waitcnt vmcnt(1)" ::: "memory"); \
    __builtin_amdgcn_sched_barrier(0); __builtin_amdgcn_s_barrier(); }
#define PIPE_WAIT_0 { asm volatile("s_waitcnt vmcnt(0)" ::: "memory"); \
    __builtin_amdgcn_sched_barrier(0); __builtin_amdgcn_s_barrier(); }

// ---------------------------------------------------------------------------
// Prep: 32-tile fragment STREAM (tile = 4KB), consumption order:
//  tiles 0-7:  V   (qkv nt = 16+t), K=32 B-frags
//  tiles 8-23: per head h: Q(2h), Q(2h+1), K(8+2h), K(9+2h)   (Q pre-scaled)
//  tiles 24-31: proj nt 0-7, K=16 u32 frags (c=0..7 per tile)
//  float 32768..33791: bias dense [h][query][key]; 33792..34175: qkv_b scaled.
// ---------------------------------------------------------------------------
__global__ void prep_kernel(const float* __restrict__ qkv_w,
                            const float* __restrict__ proj_w,
                            const float* __restrict__ bias_tbl,
                            const float* __restrict__ qkv_b,
                            u16* __restrict__ wsb, float* __restrict__ wsf)
{
    const float scale = 0.17677669529663689f;   // 32^-0.5
    int tid = blockIdx.x * 256 + threadIdx.x;
    if (tid < 49152) {                      // qkv stream tiles 0..23
        int i = tid & 7, l = (tid >> 3) & 63, w = (tid >> 9) & 3, t = tid >> 11;
        int nt;
        if (t < 8) nt = 16 + t;             // V tiles first
        else { int u = t - 8, h = u >> 2, r = u & 3;
               nt = (r < 2) ? (2 * h + r) : (8 + 2 * h + (r - 2)); }
        int k = w * 32 + (l >> 4) * 8 + i;
        int col = nt * 16 + (l & 15);
        float wv = qkv_w[k * 384 + col];
        if (col < 128) wv *= scale;         // fold softmax scale into Q
        wsb[tid] = f2b(wv);
    } else if (tid < 57344) {               // proj stream tiles 24..31
        int e = tid - 49152;
        int nt = e >> 10, rem = e & 1023;
        int c = rem >> 7, le = rem & 127, l = le >> 1, j = le & 1;
        int col = nt * 16 + (l & 15);
        int d = c * 16 + 4 * (l >> 4) + 2 * j;
        u32 val = ((u32)f2b(proj_w[(d + 1) * 128 + col]) << 16)
                |  (u32)f2b(proj_w[d * 128 + col]);
        ((u32*)wsb)[(24 + nt) * 1024 + c * 128 + l * 2 + j] = val;
    } else if (tid < 58368) {               // bias expand [h][query][key]
        int e = tid - 57344;
        int h = e >> 8, t1 = (e >> 4) & 15, t2 = e & 15;
        int idx = ((t1 >> 2) - (t2 >> 2) + 3) * 7 + ((t1 & 3) - (t2 & 3) + 3);
        wsf[32768 + e] = bias_tbl[idx * 4 + h];
    } else if (tid < 58752) {               // qkv_b, Q part pre-scaled
        int e = tid - 58368;
        wsf[33792 + e] = qkv_b[e] * (e < 128 ? scale : 1.0f);
    }
}

// ---------------------------------------------------------------------------
// Fused window attention: 4 waves/block, 1 window/wave. Weights streamed
// block-cooperatively via global_load_lds into a 3-slot ring (counted vmcnt,
// raw s_barrier). Zero shfl; zero spill-scale register state. Attention as
// R11 (direct K=16 fragments, ones-MFMA denominator).
// ---------------------------------------------------------------------------
__global__ __launch_bounds__(256, 4) void winattn_kernel(
    const float* __restrict__ x, const u16* __restrict__ wfrag,
    const float* __restrict__ proj_b, float* __restrict__ out)
{
    __shared__ alignas(16) u16 lds[19456];
    u16* ring = lds;                               // [0, 6144): 3 x 4KB slots
    float* qkvbL  = (float*)(lds + 16384);         // 384 f
    float* biasL  = (float*)(lds + 17152);         // 1024 f
    float* projbL = (float*)(lds + 19200);         // 128 f

    const int tid  = threadIdx.x;
    const int wave = tid >> 6, lane = tid & 63;
    const int g = lane >> 4, q16 = lane & 15;
    u16* vT = lds + 6144 + wave * 2560;            // per-wave [128 ch][20]

    const float* wsf = (const float*)wfrag;
    for (int e = tid; e < 384;  e += 256) qkvbL[e] = wsf[33792 + e];
    for (int e = tid; e < 1024; e += 256) biasL[e] = wsf[32768 + e];
    if (tid < 128) projbL[tid] = proj_b[tid];

    const int wid = blockIdx.x * 4 + wave;
    const int b = wid >> 10, rem = wid & 1023, wi = rem >> 5, wj = rem & 31;
    const int nTok = (wi * 4 + (q16 >> 2)) * 128 + wj * 4 + (q16 & 3);
    const float* xrow = x + ((long)b * 16384 + nTok) * 128;

    // x^T B-fragments: lane holds x[tok q16][ch = ks*32 + g*8 + i]
    F8 ax[4];
    #pragma unroll
    for (int ks = 0; ks < 4; ++ks) {
        const float4* p = (const float4*)(xrow + ks * 32 + g * 8);
        float4 v0 = p[0], v1 = p[1];
        ax[ks].u[0] = pkbf(v0.x, v0.y); ax[ks].u[1] = pkbf(v0.z, v0.w);
        ax[ks].u[2] = pkbf(v1.x, v1.y); ax[ks].u[3] = pkbf(v1.z, v1.w);
    }
    __syncthreads();    // bias tables visible; drains all vmem -> count = 0

    stage_tile(wfrag, lds, 0, wave, lane);
    stage_tile(wfrag, lds, 1, wave, lane);

    f32x4 z4 = {0.f, 0.f, 0.f, 0.f};
    F4 ones; ones.u[0] = 0x3f803f80u; ones.u[1] = 0x3f803f80u;
    u32 Opk[8][2];

    // ---- V tiles (stream 0..7) -> vT ----
    #pragma unroll
    for (int t = 0; t < 8; ++t) {
        PIPE_WAIT_1;
        const u16* slot = ring + (t % 3) * 2048;
        float4 bb = *(const float4*)&qkvbL[(16 + t) * 16 + 4 * g];
        f32x4 acc = {bb.x, bb.y, bb.z, bb.w};
        #pragma unroll
        for (int ks = 0; ks < 4; ++ks) {
            bf16x8 frag = *(const bf16x8*)(slot + ks * 512 + lane * 8);
            acc = __builtin_amdgcn_mfma_f32_16x16x32_bf16(frag, ax[ks].v, acc, 0, 0, 0);
        }
        int dbase = t * 16 + 4 * g;
        #pragma unroll
        for (int r = 0; r < 4; ++r) vT[(dbase + r) * 20 + q16] = f2b(acc[r]);
        stage_tile(wfrag, lds, t + 2, wave, lane);
    }
    asm volatile("s_waitcnt lgkmcnt(0)" ::: "memory");  // vT writes retired
    __builtin_amdgcn_sched_barrier(0);

    // ---- per-head Q,K tiles (stream 8..23) + attention ----
    #pragma unroll
    for (int h = 0; h < 4; ++h) {
        u32 Qh[2][2], Kh[2][2];
        #pragma unroll
        for (int r = 0; r < 4; ++r) {
            int t = 8 + 4 * h + r;
            PIPE_WAIT_1;
            const u16* slot = ring + (t % 3) * 2048;
            int nt = (r < 2) ? (2 * h + r) : (8 + 2 * h + (r - 2));
            float4 bb = *(const float4*)&qkvbL[nt * 16 + 4 * g];
            f32x4 acc = {bb.x, bb.y, bb.z, bb.w};
            #pragma unroll
            for (int ks = 0; ks < 4; ++ks) {
                bf16x8 frag = *(const bf16x8*)(slot + ks * 512 + lane * 8);
                acc = __builtin_amdgcn_mfma_f32_16x16x32_bf16(frag, ax[ks].v, acc, 0, 0, 0);
            }
            u32 p0 = pkbf(acc[0], acc[1]), p1 = pkbf(acc[2], acc[3]);
            if (r < 2) { Qh[r][0] = p0;     Qh[r][1] = p1; }
            else       { Kh[r - 2][0] = p0; Kh[r - 2][1] = p1; }
            stage_tile(wfrag, lds, t + 2, wave, lane);
        }
        // attention head h (no VMEM -> vmcnt untouched)
        F4 k0, k1, q0, q1;
        k0.u[0] = Kh[0][0]; k0.u[1] = Kh[0][1];
        k1.u[0] = Kh[1][0]; k1.u[1] = Kh[1][1];
        q0.u[0] = Qh[0][0]; q0.u[1] = Qh[0][1];
        q1.u[0] = Qh[1][0]; q1.u[1] = Qh[1][1];
        f32x4 s = mfma16(k0, q0, z4); s = mfma16(k1, q1, s);
        float4 bias4 = *(const float4*)&biasL[(h * 16 + q16) * 16 + 4 * g];
        float e0 = __expf(s[0] + bias4.x), e1 = __expf(s[1] + bias4.y);
        float e2 = __expf(s[2] + bias4.z), e3 = __expf(s[3] + bias4.w);
        F4 pP; pP.u[0] = pkbf(e0, e1); pP.u[1] = pkbf(e2, e3);
        f32x4 su4 = mfma16(ones, pP, z4);
        float rs = 1.0f / su4[0];
        #pragma unroll
        for (int dt = 0; dt < 2; ++dt) {
            int c = 2 * h + dt;
            F4 vf = *(const F4*)&vT[(c * 16 + q16) * 20 + 4 * g];
            f32x4 o = mfma16(vf, pP, z4);
            Opk[c][0] = pkbf(o[0] * rs, o[1] * rs);
            Opk[c][1] = pkbf(o[2] * rs, o[3] * rs);
        }
    }

    // ---- proj tiles (stream 24..31); accumulate, store after pipeline ----
    f32x4 pacc[8];
    #pragma unroll
    for (int nt = 0; nt < 8; ++nt) {
        int t = 24 + nt;
        if (t < 31) { PIPE_WAIT_1; } else { PIPE_WAIT_0; }
        const u32* slot32 = (const u32*)(ring + (t % 3) * 2048);
        float4 pb = *(const float4*)&projbL[nt * 16 + 4 * g];
        f32x4 acc = {pb.x, pb.y, pb.z, pb.w};
        #pragma unroll
        for (int c = 0; c < 8; ++c) {
            u32x2 w2 = *(const u32x2*)&slot32[c * 128 + lane * 2];
            F4 wf; wf.u[0] = w2.x; wf.u[1] = w2.y;
            F4 bO; bO.u[0] = Opk[c][0]; bO.u[1] = Opk[c][1];
            acc = mfma16(wf, bO, acc);
        }
        pacc[nt] = acc;
        if (t + 2 < 32) stage_tile(wfrag, lds, t + 2, wave, lane);
    }

    const long obase = ((long)b * 16384 + nTok) * 128;
    #pragma unroll
    for (int nt = 0; nt < 8; ++nt) {
        float4 o; o.x = pacc[nt][0]; o.y = pacc[nt][1];
        o.z = pacc[nt][2]; o.w = pacc[nt][3];
        *(float4*)&out[obase + nt * 16 + 4 * g] = o;
    }
}

extern "C" void kernel_launch(void* const* d_in, const int* in_sizes, int n_in,
                              void* d_out, int out_size, void* d_ws, size_t ws_size,
                              hipStream_t stream)
{
    const float* x        = (const float*)d_in[0];
    const float* qkv_w    = (const float*)d_in[3];
    const float* qkv_b    = (const float*)d_in[4];
    const float* proj_w   = (const float*)d_in[5];
    const float* proj_b   = (const float*)d_in[6];
    const float* bias_tbl = (const float*)d_in[7];

    u16*   wsb = (u16*)d_ws;
    float* wsf = (float*)d_ws;

    prep_kernel<<<230, 256, 0, stream>>>(qkv_w, proj_w, bias_tbl, qkv_b, wsb, wsf);
    winattn_kernel<<<4096, 256, 0, stream>>>(x, wsb, proj_b, (float*)d_out);
}

// Round 13
// 75.010 us; speedup vs baseline: 2.1988x; 1.2659x over previous
//
#include <hip/hip_runtime.h>

typedef unsigned short u16;
typedef unsigned int   u32;
typedef __attribute__((ext_vector_type(8))) short bf16x8;   // 8 bf16 = 4 VGPRs
typedef __attribute__((ext_vector_type(4))) short bf16x4;   // 4 bf16 = 2 VGPRs
typedef __attribute__((ext_vector_type(4))) float f32x4;    // MFMA 16x16 accumulator
typedef __attribute__((ext_vector_type(2))) u32 u32x2;

union F8 { bf16x8 v; u32 u[4]; };
union F4 { bf16x4 v; u32 u[2]; };

__device__ __forceinline__ u16 f2b(float f) {
    unsigned u = __builtin_bit_cast(unsigned, f);
    return (u16)((u + 0x7FFFu + ((u >> 16) & 1u)) >> 16);   // RNE fp32->bf16
}
// Bit-op RNE pack. (gfx950 lessons: asm v_cvt_pk_bf16_f32 -> 2.25e-2 error;
// _1k MFMA builtins -> NaN. Use neither.)
__device__ __forceinline__ u32 pkbf(float a, float b) {
    return ((u32)f2b(b) << 16) | (u32)f2b(a);
}

// K=16 MFMA via the proven K=32 instruction: data in k-slots 0-3, zeros in
// 4-7, identically on both operands -> exact.
__device__ __forceinline__ f32x4 mfma16(F4 a, F4 b, f32x4 c) {
    F8 a8, b8;
    a8.u[0] = a.u[0]; a8.u[1] = a.u[1]; a8.u[2] = 0; a8.u[3] = 0;
    b8.u[0] = b.u[0]; b8.u[1] = b.u[1]; b8.u[2] = 0; b8.u[3] = 0;
    return __builtin_amdgcn_mfma_f32_16x16x32_bf16(a8.v, b8.v, c, 0, 0, 0);
}

// Stage one 1KB fragment (this wave's quarter of stream tile t) into the LDS
// ring, zero VGPR cost. Stream tile t at byte t*4096; ring slot = t%3.
__device__ __forceinline__ void stage_tile(const u16* wfrag, u16* ldsbase,
                                           int t, int wave, int lane) {
    const char* gp = (const char*)wfrag + (((t * 4 + wave) << 10) | (lane << 4));
    char* lp = (char*)ldsbase + (((t % 3) << 12) | (wave << 10));
    __builtin_amdgcn_global_load_lds(
        (const __attribute__((address_space(1))) void*)gp,
        (__attribute__((address_space(3))) void*)lp, 16, 0, 0);
}

// Counted-vmcnt pipeline wait + raw barrier. vmcnt decrements IN ORDER, so
// counts may include younger stores (proj phase). Never __syncthreads here.
#define PIPE_WAIT(N) { asm volatile("s_waitcnt vmcnt(" #N ")" ::: "memory"); \
    __builtin_amdgcn_sched_barrier(0); __builtin_amdgcn_s_barrier(); }

// ---------------------------------------------------------------------------
// Prep: 32-tile fragment STREAM (tile = 4KB), consumption order:
//  tiles 0-15: per head h: Q(2h), Q(2h+1), K(8+2h), K(9+2h)  (Q pre-scaled)
//  tiles 16-23: V (qkv nt = tile index), K=32 B-frags
//  tiles 24-31: proj nt 0-7, K=16 u32 frags (c=0..7 per tile)
//  float 32768..33791: bias dense [h][query][key]; 33792..34175: qkv_b scaled.
// ---------------------------------------------------------------------------
__global__ void prep_kernel(const float* __restrict__ qkv_w,
                            const float* __restrict__ proj_w,
                            const float* __restrict__ bias_tbl,
                            const float* __restrict__ qkv_b,
                            u16* __restrict__ wsb, float* __restrict__ wsf)
{
    const float scale = 0.17677669529663689f;   // 32^-0.5
    int tid = blockIdx.x * 256 + threadIdx.x;
    if (tid < 49152) {                      // qkv stream tiles 0..23
        int i = tid & 7, l = (tid >> 3) & 63, w = (tid >> 9) & 3, t = tid >> 11;
        int nt;
        if (t < 16) { int h = t >> 2, r = t & 3;
                      nt = (r < 2) ? (2 * h + r) : (8 + 2 * h + (r - 2)); }
        else nt = t;                        // V tiles: nt = 16..23
        int k = w * 32 + (l >> 4) * 8 + i;
        int col = nt * 16 + (l & 15);
        float wv = qkv_w[k * 384 + col];
        if (col < 128) wv *= scale;         // fold softmax scale into Q
        wsb[tid] = f2b(wv);
    } else if (tid < 57344) {               // proj stream tiles 24..31
        int e = tid - 49152;
        int nt = e >> 10, rem = e & 1023;
        int c = rem >> 7, le = rem & 127, l = le >> 1, j = le & 1;
        int col = nt * 16 + (l & 15);
        int d = c * 16 + 4 * (l >> 4) + 2 * j;
        u32 val = ((u32)f2b(proj_w[(d + 1) * 128 + col]) << 16)
                |  (u32)f2b(proj_w[d * 128 + col]);
        ((u32*)wsb)[(24 + nt) * 1024 + c * 128 + l * 2 + j] = val;
    } else if (tid < 58368) {               // bias expand [h][query][key]
        int e = tid - 57344;
        int h = e >> 8, t1 = (e >> 4) & 15, t2 = e & 15;
        int idx = ((t1 >> 2) - (t2 >> 2) + 3) * 7 + ((t1 & 3) - (t2 & 3) + 3);
        wsf[32768 + e] = bias_tbl[idx * 4 + h];
    } else if (tid < 58752) {               // qkv_b, Q part pre-scaled
        int e = tid - 58368;
        wsf[33792 + e] = qkv_b[e] * (e < 128 ? scale : 1.0f);
    }
}

// ---------------------------------------------------------------------------
// Fused window attention: 4 waves/block, TWO windows/wave (A=even, B=odd wj).
// 32-tile stream shared by the window pair (16 barrier-phases/window).
// Full-K=32 MFMAs for QK (Q/K D-frag pairs concatenated; slot permutation
// identical on both operands -> exact) and proj (chunk-pair packing).
// V chunks transposed through a 640B/window scratch and consumed immediately.
// ---------------------------------------------------------------------------
__global__ __launch_bounds__(256, 4) void winattn_kernel(
    const float* __restrict__ x, const u16* __restrict__ wfrag,
    const float* __restrict__ proj_b, float* __restrict__ out)
{
    __shared__ alignas(16) u16 lds[11776];
    u16* ring = lds;                               // [0, 6144): 3 x 4KB slots
    float* qkvbL  = (float*)(lds + 8704);          // 384 f
    float* biasL  = (float*)(lds + 9472);          // 1024 f
    float* projbL = (float*)(lds + 11520);         // 128 f

    const int tid  = threadIdx.x;
    const int wave = tid >> 6, lane = tid & 63;
    const int g = lane >> 4, q16 = lane & 15;
    u16* scrA = lds + 6144 + wave * 640;           // [16 d][20] per window
    u16* scrB = scrA + 320;

    const float* wsf = (const float*)wfrag;
    for (int e = tid; e < 384;  e += 256) qkvbL[e] = wsf[33792 + e];
    for (int e = tid; e < 1024; e += 256) biasL[e] = wsf[32768 + e];
    if (tid < 128) projbL[tid] = proj_b[tid];

    const int wpair = blockIdx.x * 4 + wave;
    const int wid0  = wpair * 2;                   // window A; B = wid0+1
    const int b = wid0 >> 10, rem = wid0 & 1023, wi = rem >> 5, wj = rem & 31;
    const int nTok = (wi * 4 + (q16 >> 2)) * 128 + wj * 4 + (q16 & 3);
    const float* xrowA = x + ((long)b * 16384 + nTok) * 128;
    const float* xrowB = xrowA + 512;

    // x^T B-fragments for both windows
    F8 axA[4], axB[4];
    #pragma unroll
    for (int ks = 0; ks < 4; ++ks) {
        const float4* pA = (const float4*)(xrowA + ks * 32 + g * 8);
        float4 a0 = pA[0], a1 = pA[1];
        axA[ks].u[0] = pkbf(a0.x, a0.y); axA[ks].u[1] = pkbf(a0.z, a0.w);
        axA[ks].u[2] = pkbf(a1.x, a1.y); axA[ks].u[3] = pkbf(a1.z, a1.w);
        const float4* pB = (const float4*)(xrowB + ks * 32 + g * 8);
        float4 b0 = pB[0], b1 = pB[1];
        axB[ks].u[0] = pkbf(b0.x, b0.y); axB[ks].u[1] = pkbf(b0.z, b0.w);
        axB[ks].u[2] = pkbf(b1.x, b1.y); axB[ks].u[3] = pkbf(b1.z, b1.w);
    }
    __builtin_amdgcn_sched_barrier(0);  // pin x-loads before the drain
    __syncthreads();                    // tables visible; vmcnt drained to 0

    stage_tile(wfrag, lds, 0, wave, lane);
    stage_tile(wfrag, lds, 1, wave, lane);

    f32x4 z4 = {0.f, 0.f, 0.f, 0.f};
    F4 ones; ones.u[0] = 0x3f803f80u; ones.u[1] = 0x3f803f80u;
    F4 pPA[4], pPB[4];
    float rsA4[4], rsB4[4];
    u32 OpkA[8][2], OpkB[8][2];

    // ---- per-head Q,K tiles (stream 0..15) + attention ----
    #pragma unroll
    for (int h = 0; h < 4; ++h) {
        u32 QA[2][2], QB[2][2], KA[2][2], KB[2][2];
        #pragma unroll
        for (int r = 0; r < 4; ++r) {
            int t = 4 * h + r;
            PIPE_WAIT(1);
            const u16* slot = ring + (t % 3) * 2048;
            int nt = (r < 2) ? (2 * h + r) : (8 + 2 * h + (r - 2));
            float4 bb = *(const float4*)&qkvbL[nt * 16 + 4 * g];
            f32x4 accA = {bb.x, bb.y, bb.z, bb.w}, accB = accA;
            #pragma unroll
            for (int ks = 0; ks < 4; ++ks) {
                bf16x8 frag = *(const bf16x8*)(slot + ks * 512 + lane * 8);
                accA = __builtin_amdgcn_mfma_f32_16x16x32_bf16(frag, axA[ks].v, accA, 0, 0, 0);
                accB = __builtin_amdgcn_mfma_f32_16x16x32_bf16(frag, axB[ks].v, accB, 0, 0, 0);
            }
            u32 a0 = pkbf(accA[0], accA[1]), a1 = pkbf(accA[2], accA[3]);
            u32 b0 = pkbf(accB[0], accB[1]), b1 = pkbf(accB[2], accB[3]);
            if (r < 2) { QA[r][0] = a0; QA[r][1] = a1; QB[r][0] = b0; QB[r][1] = b1; }
            else { KA[r-2][0] = a0; KA[r-2][1] = a1; KB[r-2][0] = b0; KB[r-2][1] = b1; }
            stage_tile(wfrag, lds, t + 2, wave, lane);
        }
        // QK^T: ONE full K=32 MFMA per window (slot map identical on A and B)
        F8 kfA, qfA, kfB, qfB;
        kfA.u[0]=KA[0][0]; kfA.u[1]=KA[0][1]; kfA.u[2]=KA[1][0]; kfA.u[3]=KA[1][1];
        qfA.u[0]=QA[0][0]; qfA.u[1]=QA[0][1]; qfA.u[2]=QA[1][0]; qfA.u[3]=QA[1][1];
        kfB.u[0]=KB[0][0]; kfB.u[1]=KB[0][1]; kfB.u[2]=KB[1][0]; kfB.u[3]=KB[1][1];
        qfB.u[0]=QB[0][0]; qfB.u[1]=QB[0][1]; qfB.u[2]=QB[1][0]; qfB.u[3]=QB[1][1];
        f32x4 sA = __builtin_amdgcn_mfma_f32_16x16x32_bf16(kfA.v, qfA.v, z4, 0, 0, 0);
        f32x4 sB = __builtin_amdgcn_mfma_f32_16x16x32_bf16(kfB.v, qfB.v, z4, 0, 0, 0);

        // softmax (no max-sub; scale pre-folded); denominator via ones-MFMA
        float4 bias4 = *(const float4*)&biasL[(h * 16 + q16) * 16 + 4 * g];
        float eA0 = __expf(sA[0] + bias4.x), eA1 = __expf(sA[1] + bias4.y);
        float eA2 = __expf(sA[2] + bias4.z), eA3 = __expf(sA[3] + bias4.w);
        float eB0 = __expf(sB[0] + bias4.x), eB1 = __expf(sB[1] + bias4.y);
        float eB2 = __expf(sB[2] + bias4.z), eB3 = __expf(sB[3] + bias4.w);
        pPA[h].u[0] = pkbf(eA0, eA1); pPA[h].u[1] = pkbf(eA2, eA3);
        pPB[h].u[0] = pkbf(eB0, eB1); pPB[h].u[1] = pkbf(eB2, eB3);
        f32x4 suA = mfma16(ones, pPA[h], z4);
        f32x4 suB = mfma16(ones, pPB[h], z4);
        rsA4[h] = 1.0f / suA[0];
        rsB4[h] = 1.0f / suB[0];
    }

    // ---- V tiles (stream 16..23): chunk -> scratch transpose -> PV ----
    #pragma unroll
    for (int c = 0; c < 8; ++c) {
        int t = 16 + c;
        PIPE_WAIT(1);
        const u16* slot = ring + (t % 3) * 2048;
        float4 bb = *(const float4*)&qkvbL[(16 + c) * 16 + 4 * g];
        f32x4 accA = {bb.x, bb.y, bb.z, bb.w}, accB = accA;
        #pragma unroll
        for (int ks = 0; ks < 4; ++ks) {
            bf16x8 frag = *(const bf16x8*)(slot + ks * 512 + lane * 8);
            accA = __builtin_amdgcn_mfma_f32_16x16x32_bf16(frag, axA[ks].v, accA, 0, 0, 0);
            accB = __builtin_amdgcn_mfma_f32_16x16x32_bf16(frag, axB[ks].v, accB, 0, 0, 0);
        }
        #pragma unroll
        for (int r = 0; r < 4; ++r) {
            scrA[(4 * g + r) * 20 + q16] = f2b(accA[r]);
            scrB[(4 * g + r) * 20 + q16] = f2b(accB[r]);
        }
        asm volatile("s_waitcnt lgkmcnt(0)" ::: "memory");  // in-wave transpose
        __builtin_amdgcn_sched_barrier(0);
        F4 vfA = *(const F4*)&scrA[q16 * 20 + 4 * g];
        F4 vfB = *(const F4*)&scrB[q16 * 20 + 4 * g];
        int hh = c >> 1;
        f32x4 oA = mfma16(vfA, pPA[hh], z4);
        f32x4 oB = mfma16(vfB, pPB[hh], z4);
        float ra = rsA4[hh], rb = rsB4[hh];
        OpkA[c][0] = pkbf(oA[0] * ra, oA[1] * ra);
        OpkA[c][1] = pkbf(oA[2] * ra, oA[3] * ra);
        OpkB[c][0] = pkbf(oB[0] * rb, oB[1] * rb);
        OpkB[c][1] = pkbf(oB[2] * rb, oB[3] * rb);
        stage_tile(wfrag, lds, t + 2, wave, lane);
    }

    // ---- proj tiles (24..31): chunk-pair full-K=32; in-pipeline stores ----
    // vmcnt is FIFO: counts below account for the 4 younger stores per phase.
    const long obaseA = ((long)b * 16384 + nTok) * 128;
    const long obaseB = obaseA + 512;
    #pragma unroll
    for (int nt = 0; nt < 8; ++nt) {
        int t = 24 + nt;
        if (nt == 0)      PIPE_WAIT(1)
        else if (nt == 7) PIPE_WAIT(2)
        else              PIPE_WAIT(3)
        const u32* slot32 = (const u32*)(ring + (t % 3) * 2048);
        float4 pb = *(const float4*)&projbL[nt * 16 + 4 * g];
        f32x4 accA = {pb.x, pb.y, pb.z, pb.w}, accB = accA;
        #pragma unroll
        for (int cp = 0; cp < 4; ++cp) {
            int c = 2 * cp;
            u32x2 wa = *(const u32x2*)&slot32[c * 128 + lane * 2];
            u32x2 wb = *(const u32x2*)&slot32[(c + 1) * 128 + lane * 2];
            F8 wf; wf.u[0] = wa.x; wf.u[1] = wa.y; wf.u[2] = wb.x; wf.u[3] = wb.y;
            F8 bA; bA.u[0] = OpkA[c][0]; bA.u[1] = OpkA[c][1];
                   bA.u[2] = OpkA[c+1][0]; bA.u[3] = OpkA[c+1][1];
            F8 bB; bB.u[0] = OpkB[c][0]; bB.u[1] = OpkB[c][1];
                   bB.u[2] = OpkB[c+1][0]; bB.u[3] = OpkB[c+1][1];
            accA = __builtin_amdgcn_mfma_f32_16x16x32_bf16(wf.v, bA.v, accA, 0, 0, 0);
            accB = __builtin_amdgcn_mfma_f32_16x16x32_bf16(wf.v, bB.v, accB, 0, 0, 0);
        }
        float4 oA; oA.x = accA[0]; oA.y = accA[1]; oA.z = accA[2]; oA.w = accA[3];
        *(float4*)&out[obaseA + nt * 16 + 4 * g] = oA;
        float4 oB; oB.x = accB[0]; oB.y = accB[1]; oB.z = accB[2]; oB.w = accB[3];
        *(float4*)&out[obaseB + nt * 16 + 4 * g] = oB;
        if (nt < 6) stage_tile(wfrag, lds, t + 2, wave, lane);
    }
}

extern "C" void kernel_launch(void* const* d_in, const int* in_sizes, int n_in,
                              void* d_out, int out_size, void* d_ws, size_t ws_size,
                              hipStream_t stream)
{
    const float* x        = (const float*)d_in[0];
    const float* qkv_w    = (const float*)d_in[3];
    const float* qkv_b    = (const float*)d_in[4];
    const float* proj_w   = (const float*)d_in[5];
    const float* proj_b   = (const float*)d_in[6];
    const float* bias_tbl = (const float*)d_in[7];

    u16*   wsb = (u16*)d_ws;
    float* wsf = (float*)d_ws;

    prep_kernel<<<230, 256, 0, stream>>>(qkv_w, proj_w, bias_tbl, qkv_b, wsb, wsf);
    winattn_kernel<<<2048, 256, 0, stream>>>(x, wsb, proj_b, (float*)d_out);
}